// Round 9
// baseline (1817.457 us; speedup 1.0000x reference)
//
#include <hip/hip_runtime.h>
#include <math.h>

// Program interpreter: B=1M rows, 19 steps of MLP(2->64->64->3) + argmax walk.
// fp32 emulated on f16 MFMA, 2-limb splits (lo limb scaled 2^12, RTZ pack).
//
// R9 = R8 + register diet for 3 waves/SIMD (512-reg unified file / ~170).
//  - __launch_bounds__(256, 3)
//  - b2 C-init frags (16 AGPRs) evicted: accA starts from a zero C-frag and
//    b2 is added during the packed combine (8 VGPRs of float2 pairs).
//  - MFMA-only data (W2 limb frags, accumulators, zero frag) -> AGPR side;
//    VALU-touched data stays in VGPRs.
// Theory: latency-bound at ~1.8 waves/SIMD (R7 2x-ILP neutral, R8 -40% VALU
// neutral, no pipe saturated). 3rd wave/SIMD should cut ~30%.

#define NSTEPS 19

typedef _Float16 half8   __attribute__((ext_vector_type(8)));
typedef _Float16 half2v  __attribute__((ext_vector_type(2)));
typedef float    float2v __attribute__((ext_vector_type(2)));
typedef float    float4v __attribute__((ext_vector_type(4)));

__device__ __forceinline__ half2v pkrtz(float a, float b) {
    return __builtin_bit_cast(half2v, __builtin_amdgcn_cvt_pkrtz(a, b));
}
__device__ __forceinline__ float swz_xor16(float v) {
    // BitMode: and=0x1F, or=0, xor=16 -> lane' = lane ^ 16 (within 32-group)
    int r = __builtin_amdgcn_ds_swizzle(__builtin_bit_cast(int, v), 0x401F);
    return __builtin_bit_cast(float, r);
}
__device__ __forceinline__ float2v lo2(float4v v) {
    return __builtin_shufflevector(v, v, 0, 1);
}
__device__ __forceinline__ float2v hi2(float4v v) {
    return __builtin_shufflevector(v, v, 2, 3);
}

__global__ __launch_bounds__(256, 3)
void program_kernel(const float* __restrict__ x,
                    const float* __restrict__ W1,
                    const float* __restrict__ b1,
                    const float* __restrict__ W2,
                    const float* __restrict__ b2,
                    const float* __restrict__ W3,
                    const float* __restrict__ b3,
                    float* __restrict__ out,
                    int B) {
    const int tid    = threadIdx.x;
    const int lane   = tid & 63;
    const int wave   = tid >> 6;
    const int lanelo = lane & 15;   // m: my batch row within the tile
    const int q8     = lane >> 4;   // k-slice / replica group 0..3
    const int myRow  = blockIdx.x * 64 + wave * 16 + lanelo;
    const int rowLd  = myRow < B ? myRow : (B - 1);

    // ---- w1 tables as pairs (VGPR): pair i of kf-half: k = kf*32+q8*8+2i ----
    float2v w1a[8], w1b[8], b1v[8];
    #pragma unroll
    for (int kf = 0; kf < 2; ++kf) {
        const int k0 = kf * 32 + q8 * 8;
        const float2v* a  = (const float2v*)(W1 + k0);
        const float2v* bb = (const float2v*)(W1 + 64 + k0);
        const float2v* bv = (const float2v*)(b1 + k0);
        #pragma unroll
        for (int i = 0; i < 4; ++i) {
            w1a[kf * 4 + i] = a[i];
            w1b[kf * 4 + i] = bb[i];
            b1v[kf * 4 + i] = bv[i];
        }
    }

    // ---- W2^T limb A-frags (MFMA-only; AGPR side) ----
    half8 Wh[2][4], Wl[2][4];
    #pragma unroll
    for (int kf = 0; kf < 2; ++kf) {
        #pragma unroll
        for (int t = 0; t < 4; ++t) {
            half8 bh, bl;
            #pragma unroll
            for (int j = 0; j < 8; ++j) {
                const float w =
                    W2[(kf * 32 + q8 * 8 + j) * 64 + t * 16 + lanelo];
                const _Float16 wh = (_Float16)w;                       // RNE
                const _Float16 wl = (_Float16)((w - (float)wh) * 4096.0f);
                bh[j] = wh;
                bl[j] = wl;
            }
            Wh[kf][t] = bh;
            Wl[kf][t] = bl;
        }
    }

    // ---- b2 pairs for the combine (VGPR, 8 regs): n = 16t + 4*q8 + r ----
    float2v b2v[8];
    #pragma unroll
    for (int t = 0; t < 4; ++t) {
        const int n = t * 16 + q8 * 4;
        b2v[2 * t]     = (float2v){b2[n],     b2[n + 1]};
        b2v[2 * t + 1] = (float2v){b2[n + 2], b2[n + 3]};
    }

    // ---- W3 difference tables (VGPR): my n-set n = 16t+4*q8+r, pairs ----
    float2v d10[8], d20[8];
    #pragma unroll
    for (int p = 0; p < 8; ++p) {
        const int n0 = (p >> 1) * 16 + q8 * 4 + (p & 1) * 2;
        const float w00 = W3[n0 * 3 + 0],       w01 = W3[n0 * 3 + 1];
        const float w02 = W3[n0 * 3 + 2];
        const float w10 = W3[(n0 + 1) * 3 + 0], w11 = W3[(n0 + 1) * 3 + 1];
        const float w12 = W3[(n0 + 1) * 3 + 2];
        d10[p] = (float2v){w01 - w00, w11 - w10};
        d20[p] = (float2v){w02 - w00, w12 - w10};
    }
    const float b3v0 = b3[0];
    const float db10 = b3[1] - b3[0];
    const float db20 = b3[2] - b3[0];

    // ---- initial row state (4x replicated across q8 groups) ----
    float pos, fwd, c5;
    {
        const float* xr = x + (size_t)rowLd * 6;
        pos = xr[0];
        fwd = xr[1];
        c5  = xr[5];
    }

    const float4v zf = {0.f, 0.f, 0.f, 0.f};
    const float2v z2 = {0.f, 0.f};
    const float2v kinv = {1.0f / 4096.0f, 1.0f / 4096.0f};
    float l0 = 0.f, l1 = 0.f, l2 = 0.f;

    #pragma unroll 1
    for (int step = 0; step < NSTEPS; ++step) {
        // ---- layer 1 (packed) + 2-limb split -> B-frag limbs ----
        const float2v posp = {pos, pos}, fwdp = {fwd, fwd};
        half8 Hh[2], Hl[2];
        #pragma unroll
        for (int kf = 0; kf < 2; ++kf) {
            union { half8 v; half2v h2[4]; } uh, ul;
            #pragma unroll
            for (int p = 0; p < 4; ++p) {
                const int e = kf * 4 + p;
                float2v z = __builtin_elementwise_fma(fwdp, w1b[e], b1v[e]);
                z = __builtin_elementwise_fma(posp, w1a[e], z);
                const float2v hp = __builtin_elementwise_max(z, z2);
                uh.h2[p] = pkrtz(hp[0], hp[1]);
                const float r0 = fmaf((float)uh.h2[p][0], -1.0f, hp[0]);
                const float r1 = fmaf((float)uh.h2[p][1], -1.0f, hp[1]);
                const float2v rp = (float2v){r0, r1} * 4096.0f;  // pk_mul
                ul.h2[p] = pkrtz(rp[0], rp[1]);
            }
            Hh[kf] = uh.v;
            Hl[kf] = ul.v;
        }

        // ---- layer 2 via MFMA (zero C-inits; b2 added in combine) ----
        float4v accA[4], accB[4];
        #pragma unroll
        for (int t = 0; t < 4; ++t) {
            accB[t] = __builtin_amdgcn_mfma_f32_16x16x32_f16(
                Wl[0][t], Hh[0], zf, 0, 0, 0);
            accB[t] = __builtin_amdgcn_mfma_f32_16x16x32_f16(
                Wh[0][t], Hl[0], accB[t], 0, 0, 0);
            accB[t] = __builtin_amdgcn_mfma_f32_16x16x32_f16(
                Wl[1][t], Hh[1], accB[t], 0, 0, 0);
            accB[t] = __builtin_amdgcn_mfma_f32_16x16x32_f16(
                Wh[1][t], Hl[1], accB[t], 0, 0, 0);
            accA[t] = __builtin_amdgcn_mfma_f32_16x16x32_f16(
                Wh[0][t], Hh[0], zf, 0, 0, 0);
            accA[t] = __builtin_amdgcn_mfma_f32_16x16x32_f16(
                Wh[1][t], Hh[1], accA[t], 0, 0, 0);
        }

        // ---- h2 combine: (accA + b2) + accB/4096, relu (packed) ----
        float2v h2p[8];
        #pragma unroll
        for (int t = 0; t < 4; ++t) {
            const float2v alo = lo2(accA[t]) + b2v[2 * t];
            const float2v ahi = hi2(accA[t]) + b2v[2 * t + 1];
            h2p[2 * t] = __builtin_elementwise_max(
                __builtin_elementwise_fma(lo2(accB[t]), kinv, alo), z2);
            h2p[2 * t + 1] = __builtin_elementwise_max(
                __builtin_elementwise_fma(hi2(accB[t]), kinv, ahi), z2);
        }

        // ---- difference dots (packed) + cross-replica reduce ----
        float2v s1 = z2, s2 = z2;
        #pragma unroll
        for (int p = 0; p < 8; ++p) {
            s1 = __builtin_elementwise_fma(h2p[p], d10[p], s1);
            s2 = __builtin_elementwise_fma(h2p[p], d20[p], s2);
        }
        float g10 = s1[0] + s1[1];
        float g20 = s2[0] + s2[1];
        g10 += swz_xor16(g10);
        g20 += swz_xor16(g20);
        g10 += __shfl_xor(g10, 32, 64);
        g20 += __shfl_xor(g20, 32, 64);
        g10 += db10;   // = l1 - l0
        g20 += db20;   // = l2 - l0

        // ---- last step: reconstruct full logits for the output probs ----
        if (step == NSTEPS - 1) {
            float2v s0 = z2;
            #pragma unroll
            for (int p = 0; p < 8; ++p) {
                const int n0 = (p >> 1) * 16 + q8 * 4 + (p & 1) * 2;
                const float2v w30 = {W3[n0 * 3], W3[(n0 + 1) * 3]};
                s0 = __builtin_elementwise_fma(h2p[p], w30, s0);
            }
            float t0 = s0[0] + s0[1];
            t0 += swz_xor16(t0);
            t0 += __shfl_xor(t0, 32, 64);
            l0 = t0 + b3v0;
            l1 = l0 + g10;
            l2 = l0 + g20;
        }

        // ---- decision: l2 > max(l0,l1) <=> g20 > max(0,g10);
        //      l1 > l0 <=> g10 > 0 (first-max-wins preserved) ----
        const float delta =
            (g20 > fmaxf(0.f, g10)) ? 1.0f : ((g10 > 0.f) ? 0.0f : -1.0f);
        pos += delta;
        fwd += 1.0f;
    }

    // ---- epilogue: all lanes have their row's logits; q8==0 stores ----
    if (q8 == 0 && myRow < B) {
        const float p0 = 1.f / (1.f + __expf(-l0));
        const float p1 = 1.f / (1.f + __expf(-l1));
        const float p2 = 1.f / (1.f + __expf(-l2));
        float2* o = (float2*)(out + (size_t)myRow * 6);
        o[0] = make_float2(pos, fwd);
        o[1] = make_float2(p0, p1);
        o[2] = make_float2(p2, c5 + (float)NSTEPS);
    }
}

extern "C" void kernel_launch(void* const* d_in, const int* in_sizes, int n_in,
                              void* d_out, int out_size, void* d_ws, size_t ws_size,
                              hipStream_t stream) {
    const float* x  = (const float*)d_in[0];
    const float* W1 = (const float*)d_in[1];
    const float* b1 = (const float*)d_in[2];
    const float* W2 = (const float*)d_in[3];
    const float* b2 = (const float*)d_in[4];
    const float* W3 = (const float*)d_in[5];
    const float* b3 = (const float*)d_in[6];
    float* out = (float*)d_out;

    const int B = in_sizes[0] / 6;              // 1048576
    const int nBlocks = (B + 63) / 64;          // 64 rows/block (4 waves x 16)

    program_kernel<<<nBlocks, 256, 0, stream>>>(
        x, W1, b1, W2, b2, W3, b3, out, B);
}

// Round 10
// 702.692 us; speedup vs baseline: 2.5864x; 2.5864x over previous
//
#include <hip/hip_runtime.h>
#include <math.h>

// Program interpreter: B=1M rows, 19 steps of MLP(2->64->64->3) + argmax walk.
// fp32 emulated on f16 MFMA, 2-limb splits (lo limb scaled 2^12, RTZ pack).
//
// R10 = R8 + serial-chain surgery (R9's 3-wave push spilled -> reverted):
//  - reduce: butterfly (2 dependent DS hops) -> direct 3-fetch
//    ((v+v^16)+(v^32+v^48)): 1 swizzle + 2 bpermute, ONE latency epoch.
//  - speculative layer-1: u = pos*w1a + (fwd+1)*w1b + b1 computed during the
//    DS wait (delta-independent); post-decision h1 = relu(fma(delta,w1a,u)).
//  - accB MFMA chain 4-deep -> two independent 2-chains, summed in combine.
//  - last-step logit reconstruction peeled out of the loop.

#define NSTEPS 19

typedef _Float16 half8   __attribute__((ext_vector_type(8)));
typedef _Float16 half2v  __attribute__((ext_vector_type(2)));
typedef float    float2v __attribute__((ext_vector_type(2)));
typedef float    float4v __attribute__((ext_vector_type(4)));

__device__ __forceinline__ half2v pkrtz(float a, float b) {
    return __builtin_bit_cast(half2v, __builtin_amdgcn_cvt_pkrtz(a, b));
}
__device__ __forceinline__ float swz_xor16(float v) {
    // BitMode: and=0x1F, or=0, xor=16 -> lane' = lane ^ 16 (within 32-group)
    int r = __builtin_amdgcn_ds_swizzle(__builtin_bit_cast(int, v), 0x401F);
    return __builtin_bit_cast(float, r);
}
__device__ __forceinline__ float bperm(int addr, float v) {
    int r = __builtin_amdgcn_ds_bpermute(addr, __builtin_bit_cast(int, v));
    return __builtin_bit_cast(float, r);
}
__device__ __forceinline__ float2v lo2(float4v v) {
    return __builtin_shufflevector(v, v, 0, 1);
}
__device__ __forceinline__ float2v hi2(float4v v) {
    return __builtin_shufflevector(v, v, 2, 3);
}

__global__ __launch_bounds__(256, 2)
void program_kernel(const float* __restrict__ x,
                    const float* __restrict__ W1,
                    const float* __restrict__ b1,
                    const float* __restrict__ W2,
                    const float* __restrict__ b2,
                    const float* __restrict__ W3,
                    const float* __restrict__ b3,
                    float* __restrict__ out,
                    int B) {
    const int tid    = threadIdx.x;
    const int lane   = tid & 63;
    const int wave   = tid >> 6;
    const int lanelo = lane & 15;   // m: my batch row within the tile
    const int q8     = lane >> 4;   // k-slice / replica group 0..3
    const int myRow  = blockIdx.x * 64 + wave * 16 + lanelo;
    const int rowLd  = myRow < B ? myRow : (B - 1);

    // bpermute byte-addresses for replica partners ^32, ^48
    const int a32 = ((lane ^ 32) << 2);
    const int a48 = ((lane ^ 48) << 2);

    // ---- w1 tables as pairs (VGPR): pair i of kf-half: k = kf*32+q8*8+2i ----
    float2v w1a[8], w1b[8], b1v[8];
    #pragma unroll
    for (int kf = 0; kf < 2; ++kf) {
        const int k0 = kf * 32 + q8 * 8;
        const float2v* a  = (const float2v*)(W1 + k0);
        const float2v* bb = (const float2v*)(W1 + 64 + k0);
        const float2v* bv = (const float2v*)(b1 + k0);
        #pragma unroll
        for (int i = 0; i < 4; ++i) {
            w1a[kf * 4 + i] = a[i];
            w1b[kf * 4 + i] = bb[i];
            b1v[kf * 4 + i] = bv[i];
        }
    }

    // ---- W2^T limb A-frags (MFMA-only; AGPR side) ----
    half8 Wh[2][4], Wl[2][4];
    #pragma unroll
    for (int kf = 0; kf < 2; ++kf) {
        #pragma unroll
        for (int t = 0; t < 4; ++t) {
            half8 bh, bl;
            #pragma unroll
            for (int j = 0; j < 8; ++j) {
                const float w =
                    W2[(kf * 32 + q8 * 8 + j) * 64 + t * 16 + lanelo];
                const _Float16 wh = (_Float16)w;                       // RNE
                const _Float16 wl = (_Float16)((w - (float)wh) * 4096.0f);
                bh[j] = wh;
                bl[j] = wl;
            }
            Wh[kf][t] = bh;
            Wl[kf][t] = bl;
        }
    }

    // ---- b2 pairs for the combine (VGPR): n = 16t + 4*q8 + r ----
    float2v b2v[8];
    #pragma unroll
    for (int t = 0; t < 4; ++t) {
        const int n = t * 16 + q8 * 4;
        b2v[2 * t]     = (float2v){b2[n],     b2[n + 1]};
        b2v[2 * t + 1] = (float2v){b2[n + 2], b2[n + 3]};
    }

    // ---- W3 difference tables (VGPR): my n-set n = 16t+4*q8+r, pairs ----
    float2v d10[8], d20[8];
    #pragma unroll
    for (int p = 0; p < 8; ++p) {
        const int n0 = (p >> 1) * 16 + q8 * 4 + (p & 1) * 2;
        const float w00 = W3[n0 * 3 + 0],       w01 = W3[n0 * 3 + 1];
        const float w02 = W3[n0 * 3 + 2];
        const float w10 = W3[(n0 + 1) * 3 + 0], w11 = W3[(n0 + 1) * 3 + 1];
        const float w12 = W3[(n0 + 1) * 3 + 2];
        d10[p] = (float2v){w01 - w00, w11 - w10};
        d20[p] = (float2v){w02 - w00, w12 - w10};
    }
    const float b3v0 = b3[0];
    const float db10 = b3[1] - b3[0];
    const float db20 = b3[2] - b3[0];

    // ---- initial row state (4x replicated across q8 groups) ----
    float pos, fwd, c5;
    {
        const float* xr = x + (size_t)rowLd * 6;
        pos = xr[0];
        fwd = xr[1];
        c5  = xr[5];
    }

    const float4v zf = {0.f, 0.f, 0.f, 0.f};
    const float2v z2 = {0.f, 0.f};
    const float2v kinv = {1.0f / 4096.0f, 1.0f / 4096.0f};

    // ---- speculative pre-relu layer-1 state: u = pos*w1a + fwd*w1b + b1 ----
    float2v u[8];
    {
        const float2v posp = {pos, pos}, fwdp = {fwd, fwd};
        #pragma unroll
        for (int e = 0; e < 8; ++e) {
            u[e] = __builtin_elementwise_fma(
                posp, w1a[e],
                __builtin_elementwise_fma(fwdp, w1b[e], b1v[e]));
        }
    }

    float delta = 0.f;             // delta_{t-1}; h1_t = relu(u_t + delta*w1a)
    float g10 = 0.f, g20 = 0.f;    // last step's logit diffs
    float2v h2p[8];                // last step's hidden-2 values (for l0)

    #pragma unroll 1
    for (int step = 0; step < NSTEPS; ++step) {
        // ---- layer 1 from speculative u + 2-limb split -> B-frag limbs ----
        const float2v dp = {delta, delta};
        half8 Hh[2], Hl[2];
        #pragma unroll
        for (int kf = 0; kf < 2; ++kf) {
            union { half8 v; half2v h2[4]; } uh, ul;
            #pragma unroll
            for (int p = 0; p < 4; ++p) {
                const int e = kf * 4 + p;
                const float2v hp = __builtin_elementwise_max(
                    __builtin_elementwise_fma(dp, w1a[e], u[e]), z2);
                uh.h2[p] = pkrtz(hp[0], hp[1]);
                const float r0 = fmaf((float)uh.h2[p][0], -1.0f, hp[0]);
                const float r1 = fmaf((float)uh.h2[p][1], -1.0f, hp[1]);
                const float2v rp = (float2v){r0, r1} * 4096.0f;  // pk_mul
                ul.h2[p] = pkrtz(rp[0], rp[1]);
            }
            Hh[kf] = uh.v;
            Hl[kf] = ul.v;
        }

        // ---- layer 2 via MFMA: 3 independent 2-chains per n-tile ----
        float4v accA[4], accBx[4], accBy[4];
        #pragma unroll
        for (int t = 0; t < 4; ++t) {
            accBx[t] = __builtin_amdgcn_mfma_f32_16x16x32_f16(
                Wl[0][t], Hh[0], zf, 0, 0, 0);
            accBx[t] = __builtin_amdgcn_mfma_f32_16x16x32_f16(
                Wh[0][t], Hl[0], accBx[t], 0, 0, 0);
            accBy[t] = __builtin_amdgcn_mfma_f32_16x16x32_f16(
                Wl[1][t], Hh[1], zf, 0, 0, 0);
            accBy[t] = __builtin_amdgcn_mfma_f32_16x16x32_f16(
                Wh[1][t], Hl[1], accBy[t], 0, 0, 0);
            accA[t] = __builtin_amdgcn_mfma_f32_16x16x32_f16(
                Wh[0][t], Hh[0], zf, 0, 0, 0);
            accA[t] = __builtin_amdgcn_mfma_f32_16x16x32_f16(
                Wh[1][t], Hh[1], accA[t], 0, 0, 0);
        }

        // ---- combine: h2 = relu((accA + b2) + (accBx + accBy)/4096) ----
        #pragma unroll
        for (int t = 0; t < 4; ++t) {
            const float2v blo = lo2(accBx[t]) + lo2(accBy[t]);
            const float2v bhi = hi2(accBx[t]) + hi2(accBy[t]);
            const float2v alo = lo2(accA[t]) + b2v[2 * t];
            const float2v ahi = hi2(accA[t]) + b2v[2 * t + 1];
            h2p[2 * t] = __builtin_elementwise_max(
                __builtin_elementwise_fma(blo, kinv, alo), z2);
            h2p[2 * t + 1] = __builtin_elementwise_max(
                __builtin_elementwise_fma(bhi, kinv, ahi), z2);
        }

        // ---- difference dots (two 4-chains + add) ----
        float2v s1a = z2, s1b = z2, s2a = z2, s2b = z2;
        #pragma unroll
        for (int p = 0; p < 4; ++p) {
            s1a = __builtin_elementwise_fma(h2p[p], d10[p], s1a);
            s1b = __builtin_elementwise_fma(h2p[4 + p], d10[4 + p], s1b);
            s2a = __builtin_elementwise_fma(h2p[p], d20[p], s2a);
            s2b = __builtin_elementwise_fma(h2p[4 + p], d20[4 + p], s2b);
        }
        const float2v s1v = s1a + s1b;
        const float2v s2v = s2a + s2b;
        const float s1 = s1v[0] + s1v[1];
        const float s2 = s2v[0] + s2v[1];

        // ---- one-epoch cross-replica reduce: 1 swizzle + 2 bpermute ----
        const float s1_16 = swz_xor16(s1);
        const float s1_32 = bperm(a32, s1);
        const float s1_48 = bperm(a48, s1);
        const float s2_16 = swz_xor16(s2);
        const float s2_32 = bperm(a32, s2);
        const float s2_48 = bperm(a48, s2);

        // ---- speculative u for next step (independent of DS results) ----
        {
            const float2v posp = {pos, pos};
            const float fg = fwd + 1.0f;
            const float2v fgp = {fg, fg};
            #pragma unroll
            for (int e = 0; e < 8; ++e) {
                u[e] = __builtin_elementwise_fma(
                    posp, w1a[e],
                    __builtin_elementwise_fma(fgp, w1b[e], b1v[e]));
            }
        }

        // ---- sums (bitwise equal to butterfly by commutativity) ----
        g10 = ((s1 + s1_16) + (s1_32 + s1_48)) + db10;   // = l1 - l0
        g20 = ((s2 + s2_16) + (s2_32 + s2_48)) + db20;   // = l2 - l0

        // ---- decision: first-max-wins argmax via logit diffs ----
        delta = (g20 > fmaxf(0.f, g10)) ? 1.0f : ((g10 > 0.f) ? 0.0f : -1.0f);
        pos += delta;
        fwd += 1.0f;
    }

    // ---- reconstruct full logits from the last step's h2p ----
    float l0, l1, l2;
    {
        float2v s0a = z2, s0b = z2;
        #pragma unroll
        for (int p = 0; p < 8; ++p) {
            const int n0 = (p >> 1) * 16 + q8 * 4 + (p & 1) * 2;
            const float2v w30 = {W3[n0 * 3], W3[(n0 + 1) * 3]};
            if (p < 4) s0a = __builtin_elementwise_fma(h2p[p], w30, s0a);
            else       s0b = __builtin_elementwise_fma(h2p[p], w30, s0b);
        }
        const float2v s0v = s0a + s0b;
        const float s0 = s0v[0] + s0v[1];
        const float t16 = swz_xor16(s0);
        const float t32 = bperm(a32, s0);
        const float t48 = bperm(a48, s0);
        l0 = ((s0 + t16) + (t32 + t48)) + b3v0;
        l1 = l0 + g10;
        l2 = l0 + g20;
    }

    // ---- epilogue: all lanes have their row's logits; q8==0 stores ----
    if (q8 == 0 && myRow < B) {
        const float p0 = 1.f / (1.f + __expf(-l0));
        const float p1 = 1.f / (1.f + __expf(-l1));
        const float p2 = 1.f / (1.f + __expf(-l2));
        float2* o = (float2*)(out + (size_t)myRow * 6);
        o[0] = make_float2(pos, fwd);
        o[1] = make_float2(p0, p1);
        o[2] = make_float2(p2, c5 + (float)NSTEPS);
    }
}

extern "C" void kernel_launch(void* const* d_in, const int* in_sizes, int n_in,
                              void* d_out, int out_size, void* d_ws, size_t ws_size,
                              hipStream_t stream) {
    const float* x  = (const float*)d_in[0];
    const float* W1 = (const float*)d_in[1];
    const float* b1 = (const float*)d_in[2];
    const float* W2 = (const float*)d_in[3];
    const float* b2 = (const float*)d_in[4];
    const float* W3 = (const float*)d_in[5];
    const float* b3 = (const float*)d_in[6];
    float* out = (float*)d_out;

    const int B = in_sizes[0] / 6;              // 1048576
    const int nBlocks = (B + 63) / 64;          // 64 rows/block (4 waves x 16)

    program_kernel<<<nBlocks, 256, 0, stream>>>(
        x, W1, b1, W2, b2, W3, b3, out, B);
}